// Round 4
// baseline (214.704 us; speedup 1.0000x reference)
//
#include <hip/hip_runtime.h>
#include <stdint.h>

typedef float f32x4 __attribute__((ext_vector_type(4)));
typedef short s16x8 __attribute__((ext_vector_type(8)));
typedef unsigned short u16;

#define LOG2E 1.44269504088896340736f

__device__ __forceinline__ u16 f2bf(float f) {
    union { float f; uint32_t u; } v; v.f = f;
    uint32_t r = v.u + 0x7FFFu + ((v.u >> 16) & 1u);
    return (u16)(r >> 16);
}
__device__ __forceinline__ uint32_t pack2bf(float lo, float hi) {
    return (uint32_t)f2bf(lo) | ((uint32_t)f2bf(hi) << 16);
}
__device__ __forceinline__ float bflo2f(uint32_t u) {
    union { uint32_t u; float f; } v; v.u = u << 16; return v.f;
}
__device__ __forceinline__ float bfhi2f(uint32_t u) {
    union { uint32_t u; float f; } v; v.u = u & 0xffff0000u; return v.f;
}

// ---------------------------------------------------------------------------
// Kernel 1: QKV projection — byte-identical to rounds 2/3. Launched TWICE
// this round as an attribution probe: total = 2*qkv + attn + C, and rounds
// 2/3 give qkv + C ~= 76us, so the new total pins down qkv's real cost.
// ---------------------------------------------------------------------------
__global__ __launch_bounds__(256) void qkv_kernel(
    const float* __restrict__ x,
    const float* __restrict__ Wq, const float* __restrict__ bq,
    const float* __restrict__ Wk, const float* __restrict__ bk,
    const float* __restrict__ Wv, const float* __restrict__ bv,
    u16* __restrict__ QT, u16* __restrict__ KT, u16* __restrict__ Vg)
{
    const int tid  = threadIdx.x;
    const int lane = tid & 63;
    const int wave = tid >> 6;
    const int blk  = blockIdx.x;          // 1024 blocks
    const int b    = blk >> 8;            // batch
    const int sub  = blk & 255;
    const int jt   = sub >> 2;            // 64 j-tiles
    const int cg   = sub & 3;             // 4 channel groups of 16
    const int j    = (jt << 6) + lane;

    const float* xb = x + (size_t)b * 64 * 4096 + j;
    float xv[64];
#pragma unroll
    for (int c = 0; c < 64; ++c) xv[c] = xb[(size_t)c * 4096];

#pragma unroll
    for (int co = 0; co < 4; ++co) {
        const int row = __builtin_amdgcn_readfirstlane(cg * 16 + wave * 4 + co);
        const float* wrow = Wv + row * 64;
        float acc = bv[row];
#pragma unroll
        for (int cin = 0; cin < 64; ++cin) acc += wrow[cin] * xv[cin];
        Vg[((size_t)(b * 64 + row)) * 4096 + j] = f2bf(acc);
    }

    if (cg == 0) {
        if (wave == 0) {
            union { u16 u[8]; uint4 v; } q;
#pragma unroll
            for (int d = 0; d < 8; ++d) {
                const float* wrow = Wq + d * 64;
                float acc = bq[d];
#pragma unroll
                for (int cin = 0; cin < 64; ++cin) acc += wrow[cin] * xv[cin];
                q.u[d] = f2bf(acc * LOG2E);
            }
            *(uint4*)(QT + ((size_t)b * 4096 + j) * 8) = q.v;
        } else if (wave == 1) {
            union { u16 u[8]; uint4 v; } k;
#pragma unroll
            for (int d = 0; d < 8; ++d) {
                const float* wrow = Wk + d * 64;
                float acc = bk[d];
#pragma unroll
                for (int cin = 0; cin < 64; ++cin) acc += wrow[cin] * xv[cin];
                k.u[d] = f2bf(acc);
            }
            *(uint4*)(KT + ((size_t)b * 4096 + j) * 8) = k.v;
        }
    }
}

// ---------------------------------------------------------------------------
// Kernel 2: flash attention, no-max softmax, split-K in-block,
// SOFTWARE-PIPELINED: iteration t computes S(t) and PV(t-1).
//  - P ping-pongs between two per-wave LDS buffers: write P(t)->buf[t&1],
//    read P(t-1)<-buf[(t-1)&1] — a full iteration of slack on the LDS
//    round-trip (was the serial chain limiter).
//  - K(t+1) and V(t) prefetched one iteration ahead (vm latency hidden).
//  - DS ops are in-order per wave -> ping-pong WAR is free; compiler's
//    conservative LDS dep tracking inserts the lgkmcnt for write->read.
//  - launch_bounds (1024,4): 128-reg budget, NO spill (round 3's (1024,8)
//    forced 64 regs -> 64MB scratch writes -> regression).
// ---------------------------------------------------------------------------
#define P_STRIDE 72   // u16 elems; 144B rows, 16B-aligned for ds_read_b128
#define OXW 65        // u32 elems per packed-Ox row

__global__ __launch_bounds__(1024, 4) void attn_kernel(
    const u16* __restrict__ QT, const u16* __restrict__ KT,
    const u16* __restrict__ Vg, const float* __restrict__ x,
    const float* __restrict__ gamma, float* __restrict__ out)
{
    __shared__ u16      p_lds[16][2][16 * P_STRIDE];  // 73728 B (ping-pong)
    __shared__ uint32_t OxP[12][8 * OXW];             // 24960 B
    __shared__ float    Lx[12 * 16];                  //   768 B  -> ~99.5 KB

    const int tid  = threadIdx.x;
    const int lane = tid & 63;
    const int wave = tid >> 6;
    const int col  = lane & 15;
    const int quad = lane >> 4;
    const int qg   = wave & 3;          // query group
    const int sp   = wave >> 2;         // key split
    const int blk  = blockIdx.x;
    const int b    = blk >> 6;
    const int i0   = (blk & 63) << 6;
    const int iw   = i0 + qg * 16;      // this wave's first query

    const u16* KTb = KT + (size_t)b * 4096 * 8;
    const u16* Vb  = Vg + (size_t)b * 64 * 4096;

    const s16x8 z8 = {0,0,0,0,0,0,0,0};
    const f32x4 zero = {0.f, 0.f, 0.f, 0.f};

    // Q fragment (B operand of S^T = K.Q^T): quad0 holds Q[iw+col][0..7]
    s16x8 aq = z8;
    if (quad == 0)
        aq = *(const s16x8*)(QT + ((size_t)b * 4096 + iw + col) * 8);

    f32x4 o[4];
#pragma unroll
    for (int nt = 0; nt < 4; ++nt) o[nt] = zero;
    float lsum = 0.f;

    u16* pl0 = &p_lds[wave][0][0];
    u16* pl1 = &p_lds[wave][1][0];

    const int jbeg = sp << 10;

    // ---- prologue: K(0) frags ----
    s16x8 kb[4];
#pragma unroll
    for (int nt = 0; nt < 4; ++nt) {
        s16x8 kn = z8;
        if (quad == 0)
            kn = *(const s16x8*)(KTb + (size_t)(jbeg + nt * 16 + col) * 8);
        kb[nt] = kn;
    }
    s16x8 bvf[8];   // V(t) frags, consumed by PV in iteration t+1
    s16x8 ap0 = z8, ap1 = z8;

#pragma unroll 4
    for (int t = 0; t < 16; ++t) {
        const int j0 = jbeg + t * 64;

        // 1) S^T(t): A = K (m=key), B = Q (n=query); kb loaded last iter
        f32x4 s[4];
#pragma unroll
        for (int nt = 0; nt < 4; ++nt)
            s[nt] = __builtin_amdgcn_mfma_f32_16x16x32_bf16(kb[nt], aq, zero, 0, 0, 0);

        // 2) prefetch K(t+1)
        if (t < 15) {
#pragma unroll
            for (int nt = 0; nt < 4; ++nt) {
                s16x8 kn = z8;
                if (quad == 0)
                    kn = *(const s16x8*)(KTb + (size_t)(j0 + 64 + nt * 16 + col) * 8);
                kb[nt] = kn;
            }
        }

        // 3) read P(t-1) A-frags (written last iteration -> slack)
        if (t > 0) {
            u16* plr = ((t - 1) & 1) ? pl1 : pl0;
            ap0 = *(const s16x8*)(plr + col * P_STRIDE + quad * 8);
            ap1 = *(const s16x8*)(plr + col * P_STRIDE + 32 + quad * 8);
        }

        // 4/5) P(t) = exp2(S(t)); lsum; pack -> ds_write_b64 into buf[t&1]
        {
            u16* plw = (t & 1) ? pl1 : pl0;
#pragma unroll
            for (int nt = 0; nt < 4; ++nt) {
                float p0 = exp2f(s[nt][0]), p1 = exp2f(s[nt][1]);
                float p2 = exp2f(s[nt][2]), p3 = exp2f(s[nt][3]);
                lsum += (p0 + p1) + (p2 + p3);
                uint2 w;
                w.x = pack2bf(p0, p1);
                w.y = pack2bf(p2, p3);
                *(uint2*)(plw + col * P_STRIDE + nt * 16 + quad * 4) = w;
            }
        }

        // 6) PV(t-1): ap read in step 3 (slack = exp+pack), bvf from last iter
        if (t > 0) {
#pragma unroll
            for (int nt = 0; nt < 4; ++nt) {
                o[nt] = __builtin_amdgcn_mfma_f32_16x16x32_bf16(ap0, bvf[2 * nt],     o[nt], 0, 0, 0);
                o[nt] = __builtin_amdgcn_mfma_f32_16x16x32_bf16(ap1, bvf[2 * nt + 1], o[nt], 0, 0, 0);
            }
        }

        // 7) load V(t) for next iteration's PV(t) — full iteration of slack
#pragma unroll
        for (int nt = 0; nt < 4; ++nt) {
            const u16* vp = Vb + (size_t)(nt * 16 + col) * 4096 + j0 + quad * 8;
            bvf[2 * nt]     = *(const s16x8*)(vp);
            bvf[2 * nt + 1] = *(const s16x8*)(vp + 32);
        }
    }

    // ---- epilogue: PV(15) ----
    {
        u16* plr = pl1;   // 15 & 1
        ap0 = *(const s16x8*)(plr + col * P_STRIDE + quad * 8);
        ap1 = *(const s16x8*)(plr + col * P_STRIDE + 32 + quad * 8);
#pragma unroll
        for (int nt = 0; nt < 4; ++nt) {
            o[nt] = __builtin_amdgcn_mfma_f32_16x16x32_bf16(ap0, bvf[2 * nt],     o[nt], 0, 0, 0);
            o[nt] = __builtin_amdgcn_mfma_f32_16x16x32_bf16(ap1, bvf[2 * nt + 1], o[nt], 0, 0, 0);
        }
    }

    // ---- reduce lsum across quads: every lane -> l[query=col] ----
    lsum += __shfl_xor(lsum, 16, 64);
    lsum += __shfl_xor(lsum, 32, 64);

    // ---- combine the 4 key-splits in LDS ----
    if (sp > 0) {
        const int slice = (sp - 1) * 4 + qg;
        uint32_t* ox = &OxP[slice][0];
#pragma unroll
        for (int nt = 0; nt < 4; ++nt) {
#pragma unroll
            for (int rp = 0; rp < 2; ++rp)
                ox[(quad * 2 + rp) * OXW + nt * 16 + col] =
                    pack2bf(o[nt][2 * rp], o[nt][2 * rp + 1]);
        }
        if (quad == 0) Lx[slice * 16 + col] = lsum;
    }
    __syncthreads();
    if (sp == 0) {
        float ltot = lsum;
#pragma unroll
        for (int s = 0; s < 3; ++s)
            ltot += Lx[(s * 4 + qg) * 16 + col];
        float linv[4];
#pragma unroll
        for (int r = 0; r < 4; ++r)
            linv[r] = 1.0f / __shfl(ltot, quad * 4 + r, 16);

#pragma unroll
        for (int s = 0; s < 3; ++s) {
            const uint32_t* ox = &OxP[s * 4 + qg][0];
#pragma unroll
            for (int nt = 0; nt < 4; ++nt) {
#pragma unroll
                for (int rp = 0; rp < 2; ++rp) {
                    uint32_t u = ox[(quad * 2 + rp) * OXW + nt * 16 + col];
                    o[nt][2 * rp]     += bflo2f(u);
                    o[nt][2 * rp + 1] += bfhi2f(u);
                }
            }
        }
        const float g = gamma[0];
#pragma unroll
        for (int nt = 0; nt < 4; ++nt) {
            const int c = nt * 16 + col;
#pragma unroll
            for (int r = 0; r < 4; ++r) {
                const int i = iw + quad * 4 + r;
                const size_t idx = ((size_t)(b * 64 + c)) * 4096 + i;
                out[idx] = g * (o[nt][r] * linv[r]) + x[idx];
            }
        }
    }
}

// ---------------------------------------------------------------------------
extern "C" void kernel_launch(void* const* d_in, const int* in_sizes, int n_in,
                              void* d_out, int out_size, void* d_ws, size_t ws_size,
                              hipStream_t stream)
{
    const float* x     = (const float*)d_in[0];
    const float* Wq    = (const float*)d_in[1];
    const float* bq    = (const float*)d_in[2];
    const float* Wk    = (const float*)d_in[3];
    const float* bk    = (const float*)d_in[4];
    const float* Wv    = (const float*)d_in[5];
    const float* bv    = (const float*)d_in[6];
    const float* gamma = (const float*)d_in[7];

    u16* QT = (u16*)d_ws;                 // [4][4096][8] bf16
    u16* KT = QT + (size_t)4 * 4096 * 8;  // [4][4096][8] bf16
    u16* Vg = KT + (size_t)4 * 4096 * 8;  // [4][64][4096] bf16

    // qkv launched TWICE (idempotent) as a timing-attribution probe for the
    // constant ~76us gap between total and the attn dispatch.
    qkv_kernel<<<1024, 256, 0, stream>>>(x, Wq, bq, Wk, bk, Wv, bv, QT, KT, Vg);
    qkv_kernel<<<1024, 256, 0, stream>>>(x, Wq, bq, Wk, bk, Wv, bv, QT, KT, Vg);
    attn_kernel<<<256, 1024, 0, stream>>>(QT, KT, Vg, x, gamma, (float*)d_out);
}

// Round 5
// 157.755 us; speedup vs baseline: 1.3610x; 1.3610x over previous
//
#include <hip/hip_runtime.h>
#include <hip/hip_bf16.h>
#include <stdint.h>

typedef float f32x4 __attribute__((ext_vector_type(4)));
typedef short s16x8 __attribute__((ext_vector_type(8)));
typedef unsigned short u16;

#define LOG2E 1.44269504088896340736f

__device__ __forceinline__ u16 f2bf(float f) {
    union { float f; uint32_t u; } v; v.f = f;
    uint32_t r = v.u + 0x7FFFu + ((v.u >> 16) & 1u);
    return (u16)(r >> 16);
}
__device__ __forceinline__ uint32_t cvt2bf(float lo, float hi) {
    // single v_cvt_pk_bf16_f32 (RNE), lo in low 16 bits
    __hip_bfloat162 h = __float22bfloat162_rn(float2{lo, hi});
    union { __hip_bfloat162 h; uint32_t u; } v; v.h = h; return v.u;
}
__device__ __forceinline__ float bflo2f(uint32_t u) {
    union { uint32_t u; float f; } v; v.u = u << 16; return v.f;
}
__device__ __forceinline__ float bfhi2f(uint32_t u) {
    union { uint32_t u; float f; } v; v.u = u & 0xffff0000u; return v.f;
}

// ---------------------------------------------------------------------------
// Kernel 1: QKV projection — byte-identical body to rounds 2-4, single
// launch again (attribution probe: qkv ~= 12us, fixed overhead C ~= 66us).
// ---------------------------------------------------------------------------
__global__ __launch_bounds__(256) void qkv_kernel(
    const float* __restrict__ x,
    const float* __restrict__ Wq, const float* __restrict__ bq,
    const float* __restrict__ Wk, const float* __restrict__ bk,
    const float* __restrict__ Wv, const float* __restrict__ bv,
    u16* __restrict__ QT, u16* __restrict__ KT, u16* __restrict__ Vg)
{
    const int tid  = threadIdx.x;
    const int lane = tid & 63;
    const int wave = tid >> 6;
    const int blk  = blockIdx.x;          // 1024 blocks
    const int b    = blk >> 8;            // batch
    const int sub  = blk & 255;
    const int jt   = sub >> 2;            // 64 j-tiles
    const int cg   = sub & 3;             // 4 channel groups of 16
    const int j    = (jt << 6) + lane;

    const float* xb = x + (size_t)b * 64 * 4096 + j;
    float xv[64];
#pragma unroll
    for (int c = 0; c < 64; ++c) xv[c] = xb[(size_t)c * 4096];

#pragma unroll
    for (int co = 0; co < 4; ++co) {
        const int row = __builtin_amdgcn_readfirstlane(cg * 16 + wave * 4 + co);
        const float* wrow = Wv + row * 64;
        float acc = bv[row];
#pragma unroll
        for (int cin = 0; cin < 64; ++cin) acc += wrow[cin] * xv[cin];
        Vg[((size_t)(b * 64 + row)) * 4096 + j] = f2bf(acc);
    }

    if (cg == 0) {
        if (wave == 0) {
            union { u16 u[8]; uint4 v; } q;
#pragma unroll
            for (int d = 0; d < 8; ++d) {
                const float* wrow = Wq + d * 64;
                float acc = bq[d];
#pragma unroll
                for (int cin = 0; cin < 64; ++cin) acc += wrow[cin] * xv[cin];
                q.u[d] = f2bf(acc * LOG2E);
            }
            *(uint4*)(QT + ((size_t)b * 4096 + j) * 8) = q.v;
        } else if (wave == 1) {
            union { u16 u[8]; uint4 v; } k;
#pragma unroll
            for (int d = 0; d < 8; ++d) {
                const float* wrow = Wk + d * 64;
                float acc = bk[d];
#pragma unroll
                for (int cin = 0; cin < 64; ++cin) acc += wrow[cin] * xv[cin];
                k.u[d] = f2bf(acc);
            }
            *(uint4*)(KT + ((size_t)b * 4096 + j) * 8) = k.v;
        }
    }
}

// ---------------------------------------------------------------------------
// Kernel 2: flash attention, no-max softmax, split-K in-block.
// Software-pipelined WITHIN a 128-reg/wave budget (structural cap for a
// 1024-thread block; R4 exceeded it by holding V across iterations -> spill).
//   iter t: [read P(t-1) frags + load V(t-1)]  (issued first, consumed last)
//           S(t) = K(t).Q^T MFMA   (kb prefetched in t-1)
//           prefetch K(t+1)
//           P(t) = exp2(S(t)) -> pack -> ds_write buf[t&1]
//           PV(t-1) MFMA (ap from buf[(t-1)&1], bvf loaded this iter)
// No barriers, no waitcnt pins: DS is in-order per wave; ping-pong gives the
// LDS round-trip a full iteration of slack.
// ---------------------------------------------------------------------------
#define P_STRIDE 72   // u16 elems; 144B rows, 16B-aligned for ds_read_b128
#define OXW 65        // u32 elems per packed-Ox row

__global__ __launch_bounds__(1024) void attn_kernel(
    const u16* __restrict__ QT, const u16* __restrict__ KT,
    const u16* __restrict__ Vg, const float* __restrict__ x,
    const float* __restrict__ gamma, float* __restrict__ out)
{
    __shared__ u16      p_lds[16][2][16 * P_STRIDE];  // 73728 B
    __shared__ uint32_t OxP[12][8 * OXW];             // 24960 B
    __shared__ float    Lx[12 * 16];                  //   768 B -> ~97 KB

    const int tid  = threadIdx.x;
    const int lane = tid & 63;
    const int wave = tid >> 6;
    const int col  = lane & 15;
    const int quad = lane >> 4;
    const int qg   = wave & 3;          // query group
    const int sp   = wave >> 2;         // key split
    const int blk  = blockIdx.x;
    const int b    = blk >> 6;
    const int i0   = (blk & 63) << 6;
    const int iw   = i0 + qg * 16;      // this wave's first query

    const u16* KTb = KT + (size_t)b * 4096 * 8;
    const u16* Vb  = Vg + (size_t)b * 64 * 4096;

    const s16x8 z8 = {0,0,0,0,0,0,0,0};
    const f32x4 zero = {0.f, 0.f, 0.f, 0.f};

    // Q fragment (B operand of S^T = K.Q^T): quad0 holds Q[iw+col][0..7]
    s16x8 aq = z8;
    if (quad == 0)
        aq = *(const s16x8*)(QT + ((size_t)b * 4096 + iw + col) * 8);

    f32x4 o[4];
#pragma unroll
    for (int nt = 0; nt < 4; ++nt) o[nt] = zero;
    float lsum = 0.f;

    u16* plA = &p_lds[wave][0][0];
    u16* plB = &p_lds[wave][1][0];

    const int jbeg = sp << 10;

    // ---- prologue: K(0) frags ----
    s16x8 kb[4];
#pragma unroll
    for (int nt = 0; nt < 4; ++nt) {
        s16x8 kn = z8;
        if (quad == 0)
            kn = *(const s16x8*)(KTb + (size_t)(jbeg + nt * 16 + col) * 8);
        kb[nt] = kn;
    }
    s16x8 ap0 = z8, ap1 = z8;

#pragma unroll 2
    for (int t = 0; t < 16; ++t) {
        const int j0 = jbeg + (t << 6);
        u16* plw = (t & 1) ? plB : plA;   // P(t) target
        u16* plr = (t & 1) ? plA : plB;   // P(t-1) source

        // 1) issue P(t-1) frag reads + V(t-1) loads (consumed at step 4)
        s16x8 bvf[8];
        if (t > 0) {
            ap0 = *(const s16x8*)(plr + col * P_STRIDE + quad * 8);
            ap1 = *(const s16x8*)(plr + col * P_STRIDE + 32 + quad * 8);
#pragma unroll
            for (int nt = 0; nt < 4; ++nt) {
                const u16* vp = Vb + (size_t)(nt * 16 + col) * 4096 + (j0 - 64) + quad * 8;
                bvf[2 * nt]     = *(const s16x8*)(vp);
                bvf[2 * nt + 1] = *(const s16x8*)(vp + 32);
            }
        }

        // 2) S^T(t): A = K (m=key), B = Q (n=query)
        f32x4 s[4];
#pragma unroll
        for (int nt = 0; nt < 4; ++nt)
            s[nt] = __builtin_amdgcn_mfma_f32_16x16x32_bf16(kb[nt], aq, zero, 0, 0, 0);

        // 2b) prefetch K(t+1)
        if (t < 15) {
#pragma unroll
            for (int nt = 0; nt < 4; ++nt) {
                s16x8 kn = z8;
                if (quad == 0)
                    kn = *(const s16x8*)(KTb + (size_t)(j0 + 64 + nt * 16 + col) * 8);
                kb[nt] = kn;
            }
        }

        // 3) P(t) = exp2(S); lsum; pack (v_cvt_pk_bf16_f32) -> ds_write_b64
#pragma unroll
        for (int nt = 0; nt < 4; ++nt) {
            float p0 = exp2f(s[nt][0]), p1 = exp2f(s[nt][1]);
            float p2 = exp2f(s[nt][2]), p3 = exp2f(s[nt][3]);
            lsum += (p0 + p1) + (p2 + p3);
            uint2 w;
            w.x = cvt2bf(p0, p1);
            w.y = cvt2bf(p2, p3);
            *(uint2*)(plw + col * P_STRIDE + nt * 16 + quad * 4) = w;
        }

        // 4) PV(t-1)
        if (t > 0) {
#pragma unroll
            for (int nt = 0; nt < 4; ++nt) {
                o[nt] = __builtin_amdgcn_mfma_f32_16x16x32_bf16(ap0, bvf[2 * nt],     o[nt], 0, 0, 0);
                o[nt] = __builtin_amdgcn_mfma_f32_16x16x32_bf16(ap1, bvf[2 * nt + 1], o[nt], 0, 0, 0);
            }
        }
    }

    // ---- epilogue: PV(15) ----
    {
        const int j0 = jbeg + 15 * 64;
        ap0 = *(const s16x8*)(plB + col * P_STRIDE + quad * 8);
        ap1 = *(const s16x8*)(plB + col * P_STRIDE + 32 + quad * 8);
#pragma unroll
        for (int nt = 0; nt < 4; ++nt) {
            const u16* vp = Vb + (size_t)(nt * 16 + col) * 4096 + j0 + quad * 8;
            s16x8 bv0 = *(const s16x8*)(vp);
            s16x8 bv1 = *(const s16x8*)(vp + 32);
            o[nt] = __builtin_amdgcn_mfma_f32_16x16x32_bf16(ap0, bv0, o[nt], 0, 0, 0);
            o[nt] = __builtin_amdgcn_mfma_f32_16x16x32_bf16(ap1, bv1, o[nt], 0, 0, 0);
        }
    }

    // ---- reduce lsum across quads: every lane -> l[query=col] ----
    lsum += __shfl_xor(lsum, 16, 64);
    lsum += __shfl_xor(lsum, 32, 64);

    // ---- combine the 4 key-splits in LDS ----
    if (sp > 0) {
        const int slice = (sp - 1) * 4 + qg;
        uint32_t* ox = &OxP[slice][0];
#pragma unroll
        for (int nt = 0; nt < 4; ++nt) {
#pragma unroll
            for (int rp = 0; rp < 2; ++rp)
                ox[(quad * 2 + rp) * OXW + nt * 16 + col] =
                    cvt2bf(o[nt][2 * rp], o[nt][2 * rp + 1]);
        }
        if (quad == 0) Lx[slice * 16 + col] = lsum;
    }
    __syncthreads();
    if (sp == 0) {
        float ltot = lsum;
#pragma unroll
        for (int s = 0; s < 3; ++s)
            ltot += Lx[(s * 4 + qg) * 16 + col];
        float linv[4];
#pragma unroll
        for (int r = 0; r < 4; ++r)
            linv[r] = 1.0f / __shfl(ltot, quad * 4 + r, 16);

#pragma unroll
        for (int s = 0; s < 3; ++s) {
            const uint32_t* ox = &OxP[s * 4 + qg][0];
#pragma unroll
            for (int nt = 0; nt < 4; ++nt) {
#pragma unroll
                for (int rp = 0; rp < 2; ++rp) {
                    uint32_t u = ox[(quad * 2 + rp) * OXW + nt * 16 + col];
                    o[nt][2 * rp]     += bflo2f(u);
                    o[nt][2 * rp + 1] += bfhi2f(u);
                }
            }
        }
        const float g = gamma[0];
#pragma unroll
        for (int nt = 0; nt < 4; ++nt) {
            const int c = nt * 16 + col;
#pragma unroll
            for (int r = 0; r < 4; ++r) {
                const int i = iw + quad * 4 + r;
                const size_t idx = ((size_t)(b * 64 + c)) * 4096 + i;
                out[idx] = g * (o[nt][r] * linv[r]) + x[idx];
            }
        }
    }
}

// ---------------------------------------------------------------------------
extern "C" void kernel_launch(void* const* d_in, const int* in_sizes, int n_in,
                              void* d_out, int out_size, void* d_ws, size_t ws_size,
                              hipStream_t stream)
{
    const float* x     = (const float*)d_in[0];
    const float* Wq    = (const float*)d_in[1];
    const float* bq    = (const float*)d_in[2];
    const float* Wk    = (const float*)d_in[3];
    const float* bk    = (const float*)d_in[4];
    const float* Wv    = (const float*)d_in[5];
    const float* bv    = (const float*)d_in[6];
    const float* gamma = (const float*)d_in[7];

    u16* QT = (u16*)d_ws;                 // [4][4096][8] bf16
    u16* KT = QT + (size_t)4 * 4096 * 8;  // [4][4096][8] bf16
    u16* Vg = KT + (size_t)4 * 4096 * 8;  // [4][64][4096] bf16

    qkv_kernel<<<1024, 256, 0, stream>>>(x, Wq, bq, Wk, bk, Wv, bv, QT, KT, Vg);
    attn_kernel<<<256, 1024, 0, stream>>>(QT, KT, Vg, x, gamma, (float*)d_out);
}

// Round 8
// 149.732 us; speedup vs baseline: 1.4339x; 1.0536x over previous
//
#include <hip/hip_runtime.h>
#include <hip/hip_bf16.h>
#include <stdint.h>

typedef float f32x4 __attribute__((ext_vector_type(4)));
typedef short s16x8 __attribute__((ext_vector_type(8)));
typedef unsigned short u16;
typedef uint8_t u8;

#define LOG2E 1.44269504088896340736f
#define FP8MAX 448.0f   // OCP e4m3fn max normal

#if __has_builtin(__builtin_amdgcn_exp2f)
#define EXP2F __builtin_amdgcn_exp2f
#else
#define EXP2F exp2f
#endif

__device__ __forceinline__ u16 f2bf(float f) {
    union { float f; uint32_t u; } v; v.f = f;
    uint32_t r = v.u + 0x7FFFu + ((v.u >> 16) & 1u);
    return (u16)(r >> 16);
}
__device__ __forceinline__ uint32_t cvt2bf(float lo, float hi) {
    __hip_bfloat162 h = __float22bfloat162_rn(float2{lo, hi});
    union { __hip_bfloat162 h; uint32_t u; } v; v.h = h; return v.u;
}
__device__ __forceinline__ float bflo2f(uint32_t u) {
    union { uint32_t u; float f; } v; v.u = u << 16; return v.f;
}
__device__ __forceinline__ float bfhi2f(uint32_t u) {
    union { uint32_t u; float f; } v; v.u = u & 0xffff0000u; return v.f;
}
// pack 4 floats -> 4 fp8 e4m3 bytes (2x v_cvt_pk_fp8_f32)
__device__ __forceinline__ uint32_t cvt4fp8(float a, float b, float c, float d) {
    int w = __builtin_amdgcn_cvt_pk_fp8_f32(a, b, 0, false);   // bytes 0,1
    w     = __builtin_amdgcn_cvt_pk_fp8_f32(c, d, w, true);    // bytes 2,3
    return (uint32_t)w;
}

// ---------------------------------------------------------------------------
// Kernel 1: QKV projection. QT/KT bf16, V fp8 e4m3 (clamped; V ~ N(0,1)).
// ---------------------------------------------------------------------------
__global__ __launch_bounds__(256) void qkv_kernel(
    const float* __restrict__ x,
    const float* __restrict__ Wq, const float* __restrict__ bq,
    const float* __restrict__ Wk, const float* __restrict__ bk,
    const float* __restrict__ Wv, const float* __restrict__ bv,
    u16* __restrict__ QT, u16* __restrict__ KT, u8* __restrict__ Vg)
{
    const int tid  = threadIdx.x;
    const int lane = tid & 63;
    const int wave = tid >> 6;
    const int blk  = blockIdx.x;          // 1024 blocks
    const int b    = blk >> 8;            // batch
    const int sub  = blk & 255;
    const int jt   = sub >> 2;            // 64 j-tiles
    const int cg   = sub & 3;             // 4 channel groups of 16
    const int j    = (jt << 6) + lane;

    const float* xb = x + (size_t)b * 64 * 4096 + j;
    float xv[64];
#pragma unroll
    for (int c = 0; c < 64; ++c) xv[c] = xb[(size_t)c * 4096];

#pragma unroll
    for (int co = 0; co < 4; ++co) {
        const int row = __builtin_amdgcn_readfirstlane(cg * 16 + wave * 4 + co);
        const float* wrow = Wv + row * 64;
        float acc = bv[row];
#pragma unroll
        for (int cin = 0; cin < 64; ++cin) acc += wrow[cin] * xv[cin];
        acc = fminf(fmaxf(acc, -FP8MAX), FP8MAX);
        Vg[((size_t)(b * 64 + row)) * 4096 + j] =
            (u8)(__builtin_amdgcn_cvt_pk_fp8_f32(acc, acc, 0, false) & 0xff);
    }

    if (cg == 0) {
        if (wave == 0) {
            union { u16 u[8]; uint4 v; } q;
#pragma unroll
            for (int d = 0; d < 8; ++d) {
                const float* wrow = Wq + d * 64;
                float acc = bq[d];
#pragma unroll
                for (int cin = 0; cin < 64; ++cin) acc += wrow[cin] * xv[cin];
                q.u[d] = f2bf(acc * LOG2E);
            }
            *(uint4*)(QT + ((size_t)b * 4096 + j) * 8) = q.v;
        } else if (wave == 1) {
            union { u16 u[8]; uint4 v; } k;
#pragma unroll
            for (int d = 0; d < 8; ++d) {
                const float* wrow = Wk + d * 64;
                float acc = bk[d];
#pragma unroll
                for (int cin = 0; cin < 64; ++cin) acc += wrow[cin] * xv[cin];
                k.u[d] = f2bf(acc);
            }
            *(uint4*)(KT + ((size_t)b * 4096 + j) * 8) = k.v;
        }
    }
}

// ---------------------------------------------------------------------------
// Kernel 2: flash attention, no-max softmax, split-K in-block, pipelined.
// V and P in fp8 e4m3, PV via mfma_f32_16x16x32_fp8_fp8.
// R7 NaN root cause: P-stores (uint32_t*) and P-loads (long long*) have
// distinct TBAA types -> compiler may assume no-alias and hoist next
// iteration's ap loads above this iteration's P stores -> reads stale LDS
// junk -> 0x7F bytes decode as e4m3 NaN -> NaN output. Fix: a compiler
// ordering barrier (asm "" ::: "memory") after the P-store block. No
// waitcnt needed: LDS pipe is in-order per wave, so issue order alone
// guarantees write->read data; the compiler's own lgkmcnt covers the
// loaded-register dependency.
// ---------------------------------------------------------------------------
#define P_STRIDE 72   // BYTES per P row; 8 | 72, b64-aligned reads
#define OXW 65        // u32 elems per packed-Ox row

__global__ __launch_bounds__(1024, 4) void attn_kernel(
    const u16* __restrict__ QT, const u16* __restrict__ KT,
    const u8* __restrict__ Vg, const float* __restrict__ x,
    const float* __restrict__ gamma, float* __restrict__ out)
{
    __shared__ alignas(16) u8 p_lds[16][2][16 * P_STRIDE];  // 36864 B
    __shared__ uint32_t OxP[12][8 * OXW];                   // 24960 B
    __shared__ float    Lx[12 * 16];                        //   768 B

    const int tid  = threadIdx.x;
    const int lane = tid & 63;
    const int wave = tid >> 6;
    const int col  = lane & 15;
    const int quad = lane >> 4;
    const int qg   = wave & 3;          // query group
    const int sp   = wave >> 2;         // key split
    const int blk  = blockIdx.x;
    const int b    = blk >> 6;
    const int i0   = (blk & 63) << 6;
    const int iw   = i0 + qg * 16;      // this wave's first query

    const u16* KTb = KT + (size_t)b * 4096 * 8;
    const u8*  Vb  = Vg + (size_t)b * 64 * 4096;

    const s16x8 z8 = {0,0,0,0,0,0,0,0};
    const f32x4 zero = {0.f, 0.f, 0.f, 0.f};

    // Q fragment (B operand of S^T = K.Q^T): quad0 holds Q[iw+col][0..7]
    s16x8 aq = z8;
    if (quad == 0)
        aq = *(const s16x8*)(QT + ((size_t)b * 4096 + iw + col) * 8);

    f32x4 o[4];
#pragma unroll
    for (int nt = 0; nt < 4; ++nt) o[nt] = zero;
    float lsum = 0.f;

    u8* plA = &p_lds[wave][0][0];
    u8* plB = &p_lds[wave][1][0];

    const int jbeg = sp << 10;

    // ---- prologue: K(0) frags ----
    s16x8 kb[4];
#pragma unroll
    for (int nt = 0; nt < 4; ++nt) {
        s16x8 kn = z8;
        if (quad == 0)
            kn = *(const s16x8*)(KTb + (size_t)(jbeg + nt * 16 + col) * 8);
        kb[nt] = kn;
    }
    long long ap0 = 0, ap1 = 0;

#pragma unroll 2
    for (int t = 0; t < 16; ++t) {
        const int j0 = jbeg + (t << 6);
        u8* plw = (t & 1) ? plB : plA;   // P(t) target
        u8* plr = (t & 1) ? plA : plB;   // P(t-1) source

        // 1) issue P(t-1) frag reads (b64) + V(t-1) fp8 loads (8B/lane)
        long long bvf[8];
        if (t > 0) {
            ap0 = *(const long long*)(plr + col * P_STRIDE + quad * 8);
            ap1 = *(const long long*)(plr + col * P_STRIDE + 32 + quad * 8);
#pragma unroll
            for (int nt = 0; nt < 4; ++nt) {
                const u8* vp = Vb + (size_t)(nt * 16 + col) * 4096 + (j0 - 64) + quad * 8;
                bvf[2 * nt]     = *(const long long*)(vp);
                bvf[2 * nt + 1] = *(const long long*)(vp + 32);
            }
        }

        // 2) S^T(t): A = K (m=key), B = Q (n=query), bf16 K=32 (8 real dims)
        f32x4 s[4];
#pragma unroll
        for (int nt = 0; nt < 4; ++nt)
            s[nt] = __builtin_amdgcn_mfma_f32_16x16x32_bf16(kb[nt], aq, zero, 0, 0, 0);

        // 2b) prefetch K(t+1)
        if (t < 15) {
#pragma unroll
            for (int nt = 0; nt < 4; ++nt) {
                s16x8 kn = z8;
                if (quad == 0)
                    kn = *(const s16x8*)(KTb + (size_t)(j0 + 64 + nt * 16 + col) * 8);
                kb[nt] = kn;
            }
        }

        // 3) P(t) = min(exp2(S), 448); lsum; pack 4 fp8 -> one ds_write_b32
#pragma unroll
        for (int nt = 0; nt < 4; ++nt) {
            float p0 = fminf(EXP2F(s[nt][0]), FP8MAX);
            float p1 = fminf(EXP2F(s[nt][1]), FP8MAX);
            float p2 = fminf(EXP2F(s[nt][2]), FP8MAX);
            float p3 = fminf(EXP2F(s[nt][3]), FP8MAX);
            lsum += (p0 + p1) + (p2 + p3);
            *(uint32_t*)(plw + col * P_STRIDE + nt * 16 + quad * 4) =
                cvt4fp8(p0, p1, p2, p3);
        }
        // Compiler ordering barrier: forbid hoisting next iteration's
        // ap reads above these stores (TBAA would otherwise allow it).
        asm volatile("" ::: "memory");

        // 4) PV(t-1): fp8 MFMA, A=P (m=query), B=V (k=key, n=chan)
        if (t > 0) {
#pragma unroll
            for (int nt = 0; nt < 4; ++nt) {
                o[nt] = __builtin_amdgcn_mfma_f32_16x16x32_fp8_fp8(ap0, bvf[2 * nt],     o[nt], 0, 0, 0);
                o[nt] = __builtin_amdgcn_mfma_f32_16x16x32_fp8_fp8(ap1, bvf[2 * nt + 1], o[nt], 0, 0, 0);
            }
        }
    }

    // ---- epilogue: PV(15) ----
    {
        const int j0 = jbeg + 15 * 64;
        ap0 = *(const long long*)(plB + col * P_STRIDE + quad * 8);
        ap1 = *(const long long*)(plB + col * P_STRIDE + 32 + quad * 8);
#pragma unroll
        for (int nt = 0; nt < 4; ++nt) {
            const u8* vp = Vb + (size_t)(nt * 16 + col) * 4096 + j0 + quad * 8;
            long long bv0 = *(const long long*)(vp);
            long long bv1 = *(const long long*)(vp + 32);
            o[nt] = __builtin_amdgcn_mfma_f32_16x16x32_fp8_fp8(ap0, bv0, o[nt], 0, 0, 0);
            o[nt] = __builtin_amdgcn_mfma_f32_16x16x32_fp8_fp8(ap1, bv1, o[nt], 0, 0, 0);
        }
    }

    // ---- reduce lsum across quads: every lane -> l[query=col] ----
    lsum += __shfl_xor(lsum, 16, 64);
    lsum += __shfl_xor(lsum, 32, 64);

    // ---- combine the 4 key-splits in LDS ----
    if (sp > 0) {
        const int slice = (sp - 1) * 4 + qg;
        uint32_t* ox = &OxP[slice][0];
#pragma unroll
        for (int nt = 0; nt < 4; ++nt) {
#pragma unroll
            for (int rp = 0; rp < 2; ++rp)
                ox[(quad * 2 + rp) * OXW + nt * 16 + col] =
                    cvt2bf(o[nt][2 * rp], o[nt][2 * rp + 1]);
        }
        if (quad == 0) Lx[slice * 16 + col] = lsum;
    }
    __syncthreads();
    if (sp == 0) {
        float ltot = lsum;
#pragma unroll
        for (int s = 0; s < 3; ++s)
            ltot += Lx[(s * 4 + qg) * 16 + col];
        float linv[4];
#pragma unroll
        for (int r = 0; r < 4; ++r)
            linv[r] = 1.0f / __shfl(ltot, quad * 4 + r, 16);

#pragma unroll
        for (int s = 0; s < 3; ++s) {
            const uint32_t* ox = &OxP[s * 4 + qg][0];
#pragma unroll
            for (int nt = 0; nt < 4; ++nt) {
#pragma unroll
                for (int rp = 0; rp < 2; ++rp) {
                    uint32_t u = ox[(quad * 2 + rp) * OXW + nt * 16 + col];
                    o[nt][2 * rp]     += bflo2f(u);
                    o[nt][2 * rp + 1] += bfhi2f(u);
                }
            }
        }
        const float g = gamma[0];
#pragma unroll
        for (int nt = 0; nt < 4; ++nt) {
            const int c = nt * 16 + col;
#pragma unroll
            for (int r = 0; r < 4; ++r) {
                const int i = iw + quad * 4 + r;
                const size_t idx = ((size_t)(b * 64 + c)) * 4096 + i;
                out[idx] = g * (o[nt][r] * linv[r]) + x[idx];
            }
        }
    }
}

// ---------------------------------------------------------------------------
extern "C" void kernel_launch(void* const* d_in, const int* in_sizes, int n_in,
                              void* d_out, int out_size, void* d_ws, size_t ws_size,
                              hipStream_t stream)
{
    const float* x     = (const float*)d_in[0];
    const float* Wq    = (const float*)d_in[1];
    const float* bq    = (const float*)d_in[2];
    const float* Wk    = (const float*)d_in[3];
    const float* bk    = (const float*)d_in[4];
    const float* Wv    = (const float*)d_in[5];
    const float* bv    = (const float*)d_in[6];
    const float* gamma = (const float*)d_in[7];

    u16* QT = (u16*)d_ws;                 // [4][4096][8]  bf16
    u16* KT = QT + (size_t)4 * 4096 * 8;  // [4][4096][8]  bf16
    u8*  Vg = (u8*)(KT + (size_t)4 * 4096 * 8);  // [4][64][4096] fp8 e4m3

    qkv_kernel<<<1024, 256, 0, stream>>>(x, Wq, bq, Wk, bk, Wv, bv, QT, KT, Vg);
    attn_kernel<<<256, 1024, 0, stream>>>(QT, KT, Vg, x, gamma, (float*)d_out);
}

// Round 9
// 149.019 us; speedup vs baseline: 1.4408x; 1.0048x over previous
//
#include <hip/hip_runtime.h>
#include <hip/hip_bf16.h>
#include <stdint.h>

typedef float f32x4 __attribute__((ext_vector_type(4)));
typedef short s16x8 __attribute__((ext_vector_type(8)));
typedef unsigned short u16;
typedef uint8_t u8;

#define LOG2E 1.44269504088896340736f
#define FP8MAX 448.0f   // OCP e4m3fn max normal

#if __has_builtin(__builtin_amdgcn_exp2f)
#define EXP2F __builtin_amdgcn_exp2f
#else
#define EXP2F exp2f
#endif

__device__ __forceinline__ u16 f2bf(float f) {
    union { float f; uint32_t u; } v; v.f = f;
    uint32_t r = v.u + 0x7FFFu + ((v.u >> 16) & 1u);
    return (u16)(r >> 16);
}
__device__ __forceinline__ uint32_t cvt2bf(float lo, float hi) {
    __hip_bfloat162 h = __float22bfloat162_rn(float2{lo, hi});
    union { __hip_bfloat162 h; uint32_t u; } v; v.h = h; return v.u;
}
__device__ __forceinline__ float bflo2f(uint32_t u) {
    union { uint32_t u; float f; } v; v.u = u << 16; return v.f;
}
__device__ __forceinline__ float bfhi2f(uint32_t u) {
    union { uint32_t u; float f; } v; v.u = u & 0xffff0000u; return v.f;
}
// pack 4 floats -> 4 fp8 e4m3 bytes (2x v_cvt_pk_fp8_f32)
__device__ __forceinline__ uint32_t cvt4fp8(float a, float b, float c, float d) {
    int w = __builtin_amdgcn_cvt_pk_fp8_f32(a, b, 0, false);   // bytes 0,1
    w     = __builtin_amdgcn_cvt_pk_fp8_f32(c, d, w, true);    // bytes 2,3
    return (uint32_t)w;
}

// ---------------------------------------------------------------------------
// Kernel 1: QKV projection. QT/KT bf16, V fp8 e4m3 (clamped; V ~ N(0,1)).
// Unchanged from R8 (measured ~12us; overhead C ~66us is harness-fixed).
// ---------------------------------------------------------------------------
__global__ __launch_bounds__(256) void qkv_kernel(
    const float* __restrict__ x,
    const float* __restrict__ Wq, const float* __restrict__ bq,
    const float* __restrict__ Wk, const float* __restrict__ bk,
    const float* __restrict__ Wv, const float* __restrict__ bv,
    u16* __restrict__ QT, u16* __restrict__ KT, u8* __restrict__ Vg)
{
    const int tid  = threadIdx.x;
    const int lane = tid & 63;
    const int wave = tid >> 6;
    const int blk  = blockIdx.x;          // 1024 blocks
    const int b    = blk >> 8;            // batch
    const int sub  = blk & 255;
    const int jt   = sub >> 2;            // 64 j-tiles
    const int cg   = sub & 3;             // 4 channel groups of 16
    const int j    = (jt << 6) + lane;

    const float* xb = x + (size_t)b * 64 * 4096 + j;
    float xv[64];
#pragma unroll
    for (int c = 0; c < 64; ++c) xv[c] = xb[(size_t)c * 4096];

#pragma unroll
    for (int co = 0; co < 4; ++co) {
        const int row = __builtin_amdgcn_readfirstlane(cg * 16 + wave * 4 + co);
        const float* wrow = Wv + row * 64;
        float acc = bv[row];
#pragma unroll
        for (int cin = 0; cin < 64; ++cin) acc += wrow[cin] * xv[cin];
        acc = fminf(fmaxf(acc, -FP8MAX), FP8MAX);
        Vg[((size_t)(b * 64 + row)) * 4096 + j] =
            (u8)(__builtin_amdgcn_cvt_pk_fp8_f32(acc, acc, 0, false) & 0xff);
    }

    if (cg == 0) {
        if (wave == 0) {
            union { u16 u[8]; uint4 v; } q;
#pragma unroll
            for (int d = 0; d < 8; ++d) {
                const float* wrow = Wq + d * 64;
                float acc = bq[d];
#pragma unroll
                for (int cin = 0; cin < 64; ++cin) acc += wrow[cin] * xv[cin];
                q.u[d] = f2bf(acc * LOG2E);
            }
            *(uint4*)(QT + ((size_t)b * 4096 + j) * 8) = q.v;
        } else if (wave == 1) {
            union { u16 u[8]; uint4 v; } k;
#pragma unroll
            for (int d = 0; d < 8; ++d) {
                const float* wrow = Wk + d * 64;
                float acc = bk[d];
#pragma unroll
                for (int cin = 0; cin < 64; ++cin) acc += wrow[cin] * xv[cin];
                k.u[d] = f2bf(acc);
            }
            *(uint4*)(KT + ((size_t)b * 4096 + j) * 8) = k.v;
        }
    }
}

// ---------------------------------------------------------------------------
// Kernel 2: flash attention, fp8 V/P, no-max softmax, split-K in-block.
// R8 post-mortem: still latency-bound (all pipes <20%); residual stall is
// V-load -> PV in the SAME iteration (~180 issue-cyc slack vs ~200-400 cyc
// L2 latency). This round: V(t) loads issue at the BOTTOM of iter t and are
// consumed by PV(t) at the bottom of iter t+1 -> a full ~660-cyc iteration
// of slack. bvp held across the boundary is only 16 VGPRs in fp8 (R4's
// version of this spilled because bf16 bvf=32 under a 64-reg budget).
//   iter t: ap=P(t-1) LDS reads | S(t) MFMA | K(t+2... t+1) prefetch |
//           exp/pack/store P(t) | mem-barrier | PV(t-1) w/ bvp | V(t)->bvp
// ---------------------------------------------------------------------------
#define P_STRIDE 72   // BYTES per P row; 8 | 72, b64-aligned reads
#define OXW 65        // u32 elems per packed-Ox row

__global__ __launch_bounds__(1024, 4) void attn_kernel(
    const u16* __restrict__ QT, const u16* __restrict__ KT,
    const u8* __restrict__ Vg, const float* __restrict__ x,
    const float* __restrict__ gamma, float* __restrict__ out)
{
    __shared__ alignas(16) u8 p_lds[16][2][16 * P_STRIDE];  // 36864 B
    __shared__ uint32_t OxP[12][8 * OXW];                   // 24960 B
    __shared__ float    Lx[12 * 16];                        //   768 B

    const int tid  = threadIdx.x;
    const int lane = tid & 63;
    const int wave = tid >> 6;
    const int col  = lane & 15;
    const int quad = lane >> 4;
    const int qg   = wave & 3;          // query group
    const int sp   = wave >> 2;         // key split
    const int blk  = blockIdx.x;
    const int b    = blk >> 6;
    const int i0   = (blk & 63) << 6;
    const int iw   = i0 + qg * 16;      // this wave's first query

    const u16* KTb = KT + (size_t)b * 4096 * 8;
    const u8*  Vb  = Vg + (size_t)b * 64 * 4096;

    const s16x8 z8 = {0,0,0,0,0,0,0,0};
    const f32x4 zero = {0.f, 0.f, 0.f, 0.f};

    // Q fragment (B operand of S^T = K.Q^T): quad0 holds Q[iw+col][0..7]
    s16x8 aq = z8;
    if (quad == 0)
        aq = *(const s16x8*)(QT + ((size_t)b * 4096 + iw + col) * 8);

    f32x4 o[4];
#pragma unroll
    for (int nt = 0; nt < 4; ++nt) o[nt] = zero;
    float lsum = 0.f;

    u8* plA = &p_lds[wave][0][0];
    u8* plB = &p_lds[wave][1][0];

    const int jbeg = sp << 10;

    // ---- prologue: K(0) frags ----
    s16x8 kb[4];
#pragma unroll
    for (int nt = 0; nt < 4; ++nt) {
        s16x8 kn = z8;
        if (quad == 0)
            kn = *(const s16x8*)(KTb + (size_t)(jbeg + nt * 16 + col) * 8);
        kb[nt] = kn;
    }
    long long ap0 = 0, ap1 = 0;
    long long bvp[8];   // V(t) frags, loaded at iter t, consumed by PV at t+1

#pragma unroll 2
    for (int t = 0; t < 16; ++t) {
        const int j0 = jbeg + (t << 6);
        u8* plw = (t & 1) ? plB : plA;   // P(t) target
        u8* plr = (t & 1) ? plA : plB;   // P(t-1) source

        // 1) issue P(t-1) frag reads (b64); V already in bvp from iter t-1
        if (t > 0) {
            ap0 = *(const long long*)(plr + col * P_STRIDE + quad * 8);
            ap1 = *(const long long*)(plr + col * P_STRIDE + 32 + quad * 8);
        }

        // 2) S^T(t): A = K (m=key), B = Q (n=query), bf16 K=32 (8 real dims)
        f32x4 s[4];
#pragma unroll
        for (int nt = 0; nt < 4; ++nt)
            s[nt] = __builtin_amdgcn_mfma_f32_16x16x32_bf16(kb[nt], aq, zero, 0, 0, 0);

        // 2b) prefetch K(t+1)
        if (t < 15) {
#pragma unroll
            for (int nt = 0; nt < 4; ++nt) {
                s16x8 kn = z8;
                if (quad == 0)
                    kn = *(const s16x8*)(KTb + (size_t)(j0 + 64 + nt * 16 + col) * 8);
                kb[nt] = kn;
            }
        }

        // 3) P(t) = min(exp2(S), 448); lsum; pack 4 fp8 -> one ds_write_b32
#pragma unroll
        for (int nt = 0; nt < 4; ++nt) {
            float p0 = fminf(EXP2F(s[nt][0]), FP8MAX);
            float p1 = fminf(EXP2F(s[nt][1]), FP8MAX);
            float p2 = fminf(EXP2F(s[nt][2]), FP8MAX);
            float p3 = fminf(EXP2F(s[nt][3]), FP8MAX);
            lsum += (p0 + p1) + (p2 + p3);
            *(uint32_t*)(plw + col * P_STRIDE + nt * 16 + quad * 4) =
                cvt4fp8(p0, p1, p2, p3);
        }
        // Ordering barrier: forbid hoisting next iteration's ap reads above
        // these stores (distinct TBAA types would otherwise permit it).
        asm volatile("" ::: "memory");

        // 4) PV(t-1): fp8 MFMA; bvp was loaded LAST iteration (full slack)
        if (t > 0) {
#pragma unroll
            for (int nt = 0; nt < 4; ++nt) {
                o[nt] = __builtin_amdgcn_mfma_f32_16x16x32_fp8_fp8(ap0, bvp[2 * nt],     o[nt], 0, 0, 0);
                o[nt] = __builtin_amdgcn_mfma_f32_16x16x32_fp8_fp8(ap1, bvp[2 * nt + 1], o[nt], 0, 0, 0);
            }
        }

        // 5) V(t) loads -> bvp, consumed by PV(t) at iter t+1 (or epilogue)
#pragma unroll
        for (int nt = 0; nt < 4; ++nt) {
            const u8* vp = Vb + (size_t)(nt * 16 + col) * 4096 + j0 + quad * 8;
            bvp[2 * nt]     = *(const long long*)(vp);
            bvp[2 * nt + 1] = *(const long long*)(vp + 32);
        }
    }

    // ---- epilogue: PV(15) (P in plB, V already in bvp) ----
    {
        ap0 = *(const long long*)(plB + col * P_STRIDE + quad * 8);
        ap1 = *(const long long*)(plB + col * P_STRIDE + 32 + quad * 8);
#pragma unroll
        for (int nt = 0; nt < 4; ++nt) {
            o[nt] = __builtin_amdgcn_mfma_f32_16x16x32_fp8_fp8(ap0, bvp[2 * nt],     o[nt], 0, 0, 0);
            o[nt] = __builtin_amdgcn_mfma_f32_16x16x32_fp8_fp8(ap1, bvp[2 * nt + 1], o[nt], 0, 0, 0);
        }
    }

    // ---- reduce lsum across quads: every lane -> l[query=col] ----
    lsum += __shfl_xor(lsum, 16, 64);
    lsum += __shfl_xor(lsum, 32, 64);

    // ---- combine the 4 key-splits in LDS ----
    if (sp > 0) {
        const int slice = (sp - 1) * 4 + qg;
        uint32_t* ox = &OxP[slice][0];
#pragma unroll
        for (int nt = 0; nt < 4; ++nt) {
#pragma unroll
            for (int rp = 0; rp < 2; ++rp)
                ox[(quad * 2 + rp) * OXW + nt * 16 + col] =
                    cvt2bf(o[nt][2 * rp], o[nt][2 * rp + 1]);
        }
        if (quad == 0) Lx[slice * 16 + col] = lsum;
    }
    __syncthreads();
    if (sp == 0) {
        float ltot = lsum;
#pragma unroll
        for (int s = 0; s < 3; ++s)
            ltot += Lx[(s * 4 + qg) * 16 + col];
        float linv[4];
#pragma unroll
        for (int r = 0; r < 4; ++r)
            linv[r] = 1.0f / __shfl(ltot, quad * 4 + r, 16);

#pragma unroll
        for (int s = 0; s < 3; ++s) {
            const uint32_t* ox = &OxP[s * 4 + qg][0];
#pragma unroll
            for (int nt = 0; nt < 4; ++nt) {
#pragma unroll
                for (int rp = 0; rp < 2; ++rp) {
                    uint32_t u = ox[(quad * 2 + rp) * OXW + nt * 16 + col];
                    o[nt][2 * rp]     += bflo2f(u);
                    o[nt][2 * rp + 1] += bfhi2f(u);
                }
            }
        }
        const float g = gamma[0];
#pragma unroll
        for (int nt = 0; nt < 4; ++nt) {
            const int c = nt * 16 + col;
#pragma unroll
            for (int r = 0; r < 4; ++r) {
                const int i = iw + quad * 4 + r;
                const size_t idx = ((size_t)(b * 64 + c)) * 4096 + i;
                out[idx] = g * (o[nt][r] * linv[r]) + x[idx];
            }
        }
    }
}

// ---------------------------------------------------------------------------
extern "C" void kernel_launch(void* const* d_in, const int* in_sizes, int n_in,
                              void* d_out, int out_size, void* d_ws, size_t ws_size,
                              hipStream_t stream)
{
    const float* x     = (const float*)d_in[0];
    const float* Wq    = (const float*)d_in[1];
    const float* bq    = (const float*)d_in[2];
    const float* Wk    = (const float*)d_in[3];
    const float* bk    = (const float*)d_in[4];
    const float* Wv    = (const float*)d_in[5];
    const float* bv    = (const float*)d_in[6];
    const float* gamma = (const float*)d_in[7];

    u16* QT = (u16*)d_ws;                 // [4][4096][8]  bf16
    u16* KT = QT + (size_t)4 * 4096 * 8;  // [4][4096][8]  bf16
    u8*  Vg = (u8*)(KT + (size_t)4 * 4096 * 8);  // [4][64][4096] fp8 e4m3

    qkv_kernel<<<1024, 256, 0, stream>>>(x, Wq, bq, Wk, bk, Wv, bv, QT, KT, Vg);
    attn_kernel<<<256, 1024, 0, stream>>>(QT, KT, Vg, x, gamma, (float*)d_out);
}

// Round 10
// 104.018 us; speedup vs baseline: 2.0641x; 1.4326x over previous
//
#include <hip/hip_runtime.h>
#include <hip/hip_bf16.h>
#include <stdint.h>

typedef float f32x4 __attribute__((ext_vector_type(4)));
typedef short s16x8 __attribute__((ext_vector_type(8)));
typedef unsigned short u16;
typedef uint8_t u8;

#define LOG2E 1.44269504088896340736f
#define FP8MAX 448.0f   // OCP e4m3fn max normal

#if __has_builtin(__builtin_amdgcn_exp2f)
#define EXP2F __builtin_amdgcn_exp2f
#else
#define EXP2F exp2f
#endif

__device__ __forceinline__ u16 f2bf(float f) {
    union { float f; uint32_t u; } v; v.f = f;
    uint32_t r = v.u + 0x7FFFu + ((v.u >> 16) & 1u);
    return (u16)(r >> 16);
}
__device__ __forceinline__ uint32_t cvt2bf(float lo, float hi) {
    __hip_bfloat162 h = __float22bfloat162_rn(float2{lo, hi});
    union { __hip_bfloat162 h; uint32_t u; } v; v.h = h; return v.u;
}
__device__ __forceinline__ float bflo2f(uint32_t u) {
    union { uint32_t u; float f; } v; v.u = u << 16; return v.f;
}
__device__ __forceinline__ float bfhi2f(uint32_t u) {
    union { uint32_t u; float f; } v; v.u = u & 0xffff0000u; return v.f;
}
// pack 4 floats -> 4 fp8 e4m3 bytes (2x v_cvt_pk_fp8_f32)
__device__ __forceinline__ uint32_t cvt4fp8(float a, float b, float c, float d) {
    int w = __builtin_amdgcn_cvt_pk_fp8_f32(a, b, 0, false);   // bytes 0,1
    w     = __builtin_amdgcn_cvt_pk_fp8_f32(c, d, w, true);    // bytes 2,3
    return (uint32_t)w;
}
// 16-B LDS deposit as two b64 writes (keeps 8-B alignment req with 72-B rows)
__device__ __forceinline__ void ds_write16(u8* d, uint4 v) {
    uint2 lo; lo.x = v.x; lo.y = v.y;
    uint2 hi; hi.x = v.z; hi.y = v.w;
    *(uint2*)(d)     = lo;
    *(uint2*)(d + 8) = hi;
}

// ---------------------------------------------------------------------------
// Kernel 1: QKV projection. QT/KT bf16, V fp8 e4m3 [C][HW]. Unchanged
// (measured ~12us; fixed harness overhead C ~66us).
// ---------------------------------------------------------------------------
__global__ __launch_bounds__(256) void qkv_kernel(
    const float* __restrict__ x,
    const float* __restrict__ Wq, const float* __restrict__ bq,
    const float* __restrict__ Wk, const float* __restrict__ bk,
    const float* __restrict__ Wv, const float* __restrict__ bv,
    u16* __restrict__ QT, u16* __restrict__ KT, u8* __restrict__ Vg)
{
    const int tid  = threadIdx.x;
    const int lane = tid & 63;
    const int wave = tid >> 6;
    const int blk  = blockIdx.x;          // 1024 blocks
    const int b    = blk >> 8;            // batch
    const int sub  = blk & 255;
    const int jt   = sub >> 2;            // 64 j-tiles
    const int cg   = sub & 3;             // 4 channel groups of 16
    const int j    = (jt << 6) + lane;

    const float* xb = x + (size_t)b * 64 * 4096 + j;
    float xv[64];
#pragma unroll
    for (int c = 0; c < 64; ++c) xv[c] = xb[(size_t)c * 4096];

#pragma unroll
    for (int co = 0; co < 4; ++co) {
        const int row = __builtin_amdgcn_readfirstlane(cg * 16 + wave * 4 + co);
        const float* wrow = Wv + row * 64;
        float acc = bv[row];
#pragma unroll
        for (int cin = 0; cin < 64; ++cin) acc += wrow[cin] * xv[cin];
        acc = fminf(fmaxf(acc, -FP8MAX), FP8MAX);
        Vg[((size_t)(b * 64 + row)) * 4096 + j] =
            (u8)(__builtin_amdgcn_cvt_pk_fp8_f32(acc, acc, 0, false) & 0xff);
    }

    if (cg == 0) {
        if (wave == 0) {
            union { u16 u[8]; uint4 v; } q;
#pragma unroll
            for (int d = 0; d < 8; ++d) {
                const float* wrow = Wq + d * 64;
                float acc = bq[d];
#pragma unroll
                for (int cin = 0; cin < 64; ++cin) acc += wrow[cin] * xv[cin];
                q.u[d] = f2bf(acc * LOG2E);
            }
            *(uint4*)(QT + ((size_t)b * 4096 + j) * 8) = q.v;
        } else if (wave == 1) {
            union { u16 u[8]; uint4 v; } k;
#pragma unroll
            for (int d = 0; d < 8; ++d) {
                const float* wrow = Wk + d * 64;
                float acc = bk[d];
#pragma unroll
                for (int cin = 0; cin < 64; ++cin) acc += wrow[cin] * xv[cin];
                k.u[d] = f2bf(acc);
            }
            *(uint4*)(KT + ((size_t)b * 4096 + j) * 8) = k.v;
        }
    }
}

// ---------------------------------------------------------------------------
// Kernel 2: flash attention, fp8 V/P, split-K in-block, LDS-STAGED V.
// R9 diagnosis: TA/L1 line-lookup saturation — V[C][HW] frag loads have
// lane-stride 4096 (16 lines/instr, ~2300 line-ops per 2660-cyc CU slot).
// Fix: the 4 qg-waves of each split share one 4KB V tile in LDS.
//   iter t: stage-load V(t+1) quarter (1 coalesced uint4/lane; 16 lines/wave)
//           ap=P(t-1) | S(t) mfma | K(t+1) prefetch | exp/pack->P(t)
//           vf=V(t-1) frags from vbuf[(t-1)&1] (ds_read_b64, <=2-way) | PV(t-1)
//           __syncthreads  (publishes P+V stages; vmcnt drain covered by
//                           the full iteration since the stage was issued)
//           ds_write V(t+1) -> vbuf[(t+1)&1]  (post-barrier: its previous
//           occupant V(t-1) was last read pre-barrier this iter)
// ---------------------------------------------------------------------------
#define P_STRIDE 72   // BYTES per P row (64 fp8 + 8 pad)
#define VROW 72       // BYTES per V-tile row (64 fp8 + 8 pad; 8 | 72)
#define OXW 65        // u32 elems per packed-Ox row

__global__ __launch_bounds__(1024, 4) void attn_kernel(
    const u16* __restrict__ QT, const u16* __restrict__ KT,
    const u8* __restrict__ Vg, const float* __restrict__ x,
    const float* __restrict__ gamma, float* __restrict__ out)
{
    __shared__ alignas(16) u8 p_lds[16][2][16 * P_STRIDE];  // 36864 B
    __shared__ alignas(16) u8 vbuf[4][2][64 * VROW];        // 36864 B
    __shared__ uint32_t OxP[12][8 * OXW];                   // 24960 B
    __shared__ float    Lx[12 * 16];                        //   768 B ~99.5KB

    const int tid  = threadIdx.x;
    const int lane = tid & 63;
    const int wave = tid >> 6;
    const int col  = lane & 15;
    const int quad = lane >> 4;
    const int qg   = wave & 3;          // query group
    const int sp   = wave >> 2;         // key split
    const int blk  = blockIdx.x;
    const int b    = blk >> 6;
    const int i0   = (blk & 63) << 6;
    const int iw   = i0 + qg * 16;      // this wave's first query

    const u16* KTb = KT + (size_t)b * 4096 * 8;
    const u8*  Vb  = Vg + (size_t)b * 64 * 4096;

    const s16x8 z8 = {0,0,0,0,0,0,0,0};
    const f32x4 zero = {0.f, 0.f, 0.f, 0.f};

    // Q fragment (B operand of S^T = K.Q^T): quad0 holds Q[iw+col][0..7]
    s16x8 aq = z8;
    if (quad == 0)
        aq = *(const s16x8*)(QT + ((size_t)b * 4096 + iw + col) * 8);

    f32x4 o[4];
#pragma unroll
    for (int nt = 0; nt < 4; ++nt) o[nt] = zero;
    float lsum = 0.f;

    u8* plA = &p_lds[wave][0][0];
    u8* plB = &p_lds[wave][1][0];

    // V staging role of this lane: channel row srow, 16-B chunk schk
    const int srow = (qg << 4) + (lane >> 2);
    const int schk = lane & 3;
    const u8* vsrc = Vb + (size_t)srow * 4096 + schk * 16;
    u8* vdst0 = &vbuf[sp][0][srow * VROW + schk * 16];
    u8* vdst1 = &vbuf[sp][1][srow * VROW + schk * 16];

    const int jbeg = sp << 10;

    // ---- prologue: K(0) frags + stage V(0) into vbuf[0] ----
    s16x8 kb[4];
#pragma unroll
    for (int nt = 0; nt < 4; ++nt) {
        s16x8 kn = z8;
        if (quad == 0)
            kn = *(const s16x8*)(KTb + (size_t)(jbeg + nt * 16 + col) * 8);
        kb[nt] = kn;
    }
    ds_write16(vdst0, *(const uint4*)(vsrc + jbeg));

    long long ap0 = 0, ap1 = 0;

#pragma unroll 2
    for (int t = 0; t < 16; ++t) {
        const int j0 = jbeg + (t << 6);
        u8* plw = (t & 1) ? plB : plA;   // P(t) target
        u8* plr = (t & 1) ? plA : plB;   // P(t-1) source

        // 0) stage-load V(t+1) tile quarter (coalesced; lands by the barrier)
        uint4 vstg;
        if (t < 15) vstg = *(const uint4*)(vsrc + j0 + 64);

        // 1) P(t-1) frag reads
        if (t > 0) {
            ap0 = *(const long long*)(plr + col * P_STRIDE + quad * 8);
            ap1 = *(const long long*)(plr + col * P_STRIDE + 32 + quad * 8);
        }

        // 2) S^T(t): A = K (m=key), B = Q (n=query), bf16 K=32 (8 real dims)
        f32x4 s[4];
#pragma unroll
        for (int nt = 0; nt < 4; ++nt)
            s[nt] = __builtin_amdgcn_mfma_f32_16x16x32_bf16(kb[nt], aq, zero, 0, 0, 0);

        // 2b) prefetch K(t+1)
        if (t < 15) {
#pragma unroll
            for (int nt = 0; nt < 4; ++nt) {
                s16x8 kn = z8;
                if (quad == 0)
                    kn = *(const s16x8*)(KTb + (size_t)(j0 + 64 + nt * 16 + col) * 8);
                kb[nt] = kn;
            }
        }

        // 3) P(t) = min(exp2(S), 448); lsum; pack 4 fp8 -> one ds_write_b32
#pragma unroll
        for (int nt = 0; nt < 4; ++nt) {
            float p0 = fminf(EXP2F(s[nt][0]), FP8MAX);
            float p1 = fminf(EXP2F(s[nt][1]), FP8MAX);
            float p2 = fminf(EXP2F(s[nt][2]), FP8MAX);
            float p3 = fminf(EXP2F(s[nt][3]), FP8MAX);
            lsum += (p0 + p1) + (p2 + p3);
            *(uint32_t*)(plw + col * P_STRIDE + nt * 16 + quad * 4) =
                cvt4fp8(p0, p1, p2, p3);
        }
        // Ordering barrier: forbid hoisting next iteration's ap reads above
        // these stores (distinct TBAA types would otherwise permit it).
        asm volatile("" ::: "memory");

        // 4) V(t-1) frags from LDS tile + PV(t-1)
        if (t > 0) {
            const u8* vt = &vbuf[sp][(t - 1) & 1][0];
#pragma unroll
            for (int nt = 0; nt < 4; ++nt) {
                long long b0 = *(const long long*)(vt + (nt * 16 + col) * VROW + quad * 8);
                long long b1 = *(const long long*)(vt + (nt * 16 + col) * VROW + quad * 8 + 32);
                o[nt] = __builtin_amdgcn_mfma_f32_16x16x32_fp8_fp8(ap0, b0, o[nt], 0, 0, 0);
                o[nt] = __builtin_amdgcn_mfma_f32_16x16x32_fp8_fp8(ap1, b1, o[nt], 0, 0, 0);
            }
        }

        // 5) publish: P(t) (intra-wave anyway) and V(t+1) staging order
        __syncthreads();

        // 6) deposit V(t+1) into vbuf[(t+1)&1] (old occupant V(t-1) was last
        //    read pre-barrier this iteration; next barrier publishes it)
        if (t < 15) ds_write16((t & 1) ? vdst0 : vdst1, vstg);
    }

    // ---- epilogue: PV(15): P in plB, V(15) in vbuf[sp][1] ----
    {
        ap0 = *(const long long*)(plB + col * P_STRIDE + quad * 8);
        ap1 = *(const long long*)(plB + col * P_STRIDE + 32 + quad * 8);
        const u8* vt = &vbuf[sp][1][0];
#pragma unroll
        for (int nt = 0; nt < 4; ++nt) {
            long long b0 = *(const long long*)(vt + (nt * 16 + col) * VROW + quad * 8);
            long long b1 = *(const long long*)(vt + (nt * 16 + col) * VROW + quad * 8 + 32);
            o[nt] = __builtin_amdgcn_mfma_f32_16x16x32_fp8_fp8(ap0, b0, o[nt], 0, 0, 0);
            o[nt] = __builtin_amdgcn_mfma_f32_16x16x32_fp8_fp8(ap1, b1, o[nt], 0, 0, 0);
        }
    }

    // ---- reduce lsum across quads: every lane -> l[query=col] ----
    lsum += __shfl_xor(lsum, 16, 64);
    lsum += __shfl_xor(lsum, 32, 64);

    // ---- combine the 4 key-splits in LDS ----
    if (sp > 0) {
        const int slice = (sp - 1) * 4 + qg;
        uint32_t* ox = &OxP[slice][0];
#pragma unroll
        for (int nt = 0; nt < 4; ++nt) {
#pragma unroll
            for (int rp = 0; rp < 2; ++rp)
                ox[(quad * 2 + rp) * OXW + nt * 16 + col] =
                    cvt2bf(o[nt][2 * rp], o[nt][2 * rp + 1]);
        }
        if (quad == 0) Lx[slice * 16 + col] = lsum;
    }
    __syncthreads();
    if (sp == 0) {
        float ltot = lsum;
#pragma unroll
        for (int s = 0; s < 3; ++s)
            ltot += Lx[(s * 4 + qg) * 16 + col];
        float linv[4];
#pragma unroll
        for (int r = 0; r < 4; ++r)
            linv[r] = 1.0f / __shfl(ltot, quad * 4 + r, 16);

#pragma unroll
        for (int s = 0; s < 3; ++s) {
            const uint32_t* ox = &OxP[s * 4 + qg][0];
#pragma unroll
            for (int nt = 0; nt < 4; ++nt) {
#pragma unroll
                for (int rp = 0; rp < 2; ++rp) {
                    uint32_t u = ox[(quad * 2 + rp) * OXW + nt * 16 + col];
                    o[nt][2 * rp]     += bflo2f(u);
                    o[nt][2 * rp + 1] += bfhi2f(u);
                }
            }
        }
        const float g = gamma[0];
#pragma unroll
        for (int nt = 0; nt < 4; ++nt) {
            const int c = nt * 16 + col;
#pragma unroll
            for (int r = 0; r < 4; ++r) {
                const int i = iw + quad * 4 + r;
                const size_t idx = ((size_t)(b * 64 + c)) * 4096 + i;
                out[idx] = g * (o[nt][r] * linv[r]) + x[idx];
            }
        }
    }
}

// ---------------------------------------------------------------------------
extern "C" void kernel_launch(void* const* d_in, const int* in_sizes, int n_in,
                              void* d_out, int out_size, void* d_ws, size_t ws_size,
                              hipStream_t stream)
{
    const float* x     = (const float*)d_in[0];
    const float* Wq    = (const float*)d_in[1];
    const float* bq    = (const float*)d_in[2];
    const float* Wk    = (const float*)d_in[3];
    const float* bk    = (const float*)d_in[4];
    const float* Wv    = (const float*)d_in[5];
    const float* bv    = (const float*)d_in[6];
    const float* gamma = (const float*)d_in[7];

    u16* QT = (u16*)d_ws;                 // [4][4096][8]  bf16
    u16* KT = QT + (size_t)4 * 4096 * 8;  // [4][4096][8]  bf16
    u8*  Vg = (u8*)(KT + (size_t)4 * 4096 * 8);  // [4][64][4096] fp8 e4m3

    qkv_kernel<<<1024, 256, 0, stream>>>(x, Wq, bq, Wk, bk, Wv, bv, QT, KT, Vg);
    attn_kernel<<<256, 1024, 0, stream>>>(QT, KT, Vg, x, gamma, (float*)d_out);
}